// Round 4
// baseline (607.174 us; speedup 1.0000x reference)
//
#include <hip/hip_runtime.h>

typedef __attribute__((ext_vector_type(8))) short bf16x8;
typedef __attribute__((ext_vector_type(4))) float f32x4;
typedef __attribute__((ext_vector_type(4))) unsigned short u16x4;

#define DEVFN static __device__ __forceinline__

DEVFN unsigned short f2b(float f) {   // f32 -> bf16, round-to-nearest-even
  union { float f; unsigned u; } x; x.f = f;
  unsigned r = x.u + 0x7FFFu + ((x.u >> 16) & 1u);
  return (unsigned short)(r >> 16);
}

DEVFN void gll16(const void* g, void* l) {  // async global->LDS, 16B per lane
  __builtin_amdgcn_global_load_lds(
      (const __attribute__((address_space(1))) unsigned int*)g,
      (__attribute__((address_space(3))) unsigned int*)l, 16, 0, 0);
}

#define MFMA16(a, b, c) __builtin_amdgcn_mfma_f32_16x16x32_bf16((a), (b), (c), 0, 0, 0)

// ---------------- prep: cast + transpose weights to bf16 ----------------
__global__ __launch_bounds__(256) void prep_kernel(
    const float* __restrict__ Wq, const float* __restrict__ Wk, const float* __restrict__ Wv,
    const float* __restrict__ Wo, const float* __restrict__ W1, const float* __restrict__ W2,
    short* __restrict__ wqkvT, short* __restrict__ woT,
    short* __restrict__ w1T, short* __restrict__ w2T)
{
  int idx = blockIdx.x * 256 + threadIdx.x;
  if (idx < 442368) {
    int n = idx / 384, kk = idx - n * 384;
    int sec = n / 384, ww = n - sec * 384;
    const float* s = sec == 0 ? Wq : (sec == 1 ? Wk : Wv);
    wqkvT[idx] = (short)f2b(s[kk * 384 + ww]);
  } else if (idx < 589824) {
    int j = idx - 442368;
    int n = j / 384, kk = j - n * 384;
    woT[j] = (short)f2b(Wo[kk * 384 + n]);
  } else if (idx < 1179648) {
    int j = idx - 589824;
    int n = j / 384, kk = j - n * 384;
    w1T[j] = (short)f2b(W1[kk * 1536 + n]);
  } else if (idx < 1769472) {
    int j = idx - 1179648;
    int n = j / 1536, kk = j - n * 1536;
    w2T[j] = (short)f2b(W2[kk * 384 + n]);
  }
}

// ---------------- LayerNorm: f32 in -> bf16 out, 1 wave per row of 384 ----
__global__ __launch_bounds__(256) void ln_kernel(
    const float* __restrict__ x, const float* __restrict__ g, const float* __restrict__ b,
    short* __restrict__ out)
{
  int row = blockIdx.x * 4 + (threadIdx.x >> 6);
  int l = threadIdx.x & 63;
  const float* xr = x + (size_t)row * 384;
  float v[6], s = 0.f, s2 = 0.f;
  #pragma unroll
  for (int i = 0; i < 6; ++i) { v[i] = xr[l + 64 * i]; s += v[i]; s2 += v[i] * v[i]; }
  #pragma unroll
  for (int m = 1; m < 64; m <<= 1) { s += __shfl_xor(s, m); s2 += __shfl_xor(s2, m); }
  float mu = s * (1.f / 384.f);
  float rs = rsqrtf(s2 * (1.f / 384.f) - mu * mu + 1e-5f);
  short* orow = out + (size_t)row * 384;
  #pragma unroll
  for (int i = 0; i < 6; ++i) {
    int c = l + 64 * i;
    orow[c] = (short)f2b((v[i] - mu) * rs * g[c] + b[c]);
  }
}

// ---------------- GEMM: C[M,N] = A[M,K] * BT[N,K]^T, bf16 MFMA ------------
// 256x128 tile, BK=64, 512 threads = 8 waves (4x2), wave = 64x64 (4x4 frags).
// 1D grid, XCD-chunked bijective swizzle, x-fastest within chunk.
// LDS XOR-swizzled (granule ^= row&7) via pre-swizzled global source.
// EPI 0: QKV split (q scaled 0.125, v stored [B,H,D,T])
// EPI 1: f32 out = acc + bias[col] + resid[row,col]   (fout may alias resid)
// EPI 2: bf16 out = relu(acc + bias[col])
template<int EPI>
__global__ __launch_bounds__(512) void gemm_bt(
    const short* __restrict__ A, const short* __restrict__ BT,
    int K, int kt, int N, int nx,
    const float* __restrict__ bias, const float* __restrict__ resid,
    float* __restrict__ fout, short* __restrict__ bout,
    short* __restrict__ qb, short* __restrict__ kb, short* __restrict__ vb)
{
  __shared__ short As[256 * 64];
  __shared__ short Bs[128 * 64];
  const int tid = threadIdx.x;
  const int l = tid & 63, w = tid >> 6;
  const int cl = l & 15, rq = l >> 4;
  const int wr = (w >> 1) * 64, wc = (w & 1) * 64;

  // bijective XCD-chunk swizzle
  const int nwg = gridDim.x, bid = blockIdx.x;
  const int q8 = nwg >> 3, r8 = nwg & 7;
  const int xcd = bid & 7, ii = bid >> 3;
  const int wg = (xcd < r8) ? xcd * (q8 + 1) + ii : r8 * (q8 + 1) + (xcd - r8) * q8 + ii;
  const int bx = wg % nx, by = wg / nx;

  const int m0 = by * 256, n0 = bx * 128;
  const short* Ab = A + (size_t)m0 * K;
  const short* Bb = BT + (size_t)n0 * K;

  f32x4 acc[4][4] = {};

  for (int ks = 0; ks < kt; ++ks) {
    const int k0 = ks * 64;
    __syncthreads();
    #pragma unroll
    for (int i = 0; i < 4; ++i) {
      int slot = i * 512 + tid;
      int row = slot >> 3, g = slot & 7;
      int gs = g ^ (row & 7);
      gll16(Ab + (size_t)row * K + k0 + gs * 8, &As[slot * 8]);
    }
    #pragma unroll
    for (int i = 0; i < 2; ++i) {
      int slot = i * 512 + tid;
      int row = slot >> 3, g = slot & 7;
      int gs = g ^ (row & 7);
      gll16(Bb + (size_t)row * K + k0 + gs * 8, &Bs[slot * 8]);
    }
    __syncthreads();
    #pragma unroll
    for (int kk = 0; kk < 2; ++kk) {
      bf16x8 af[4], bfr[4];
      #pragma unroll
      for (int m = 0; m < 4; ++m) {
        int row = wr + m * 16 + cl;
        af[m] = *(const bf16x8*)&As[row * 64 + (((kk * 4 + rq) ^ (row & 7)) * 8)];
      }
      #pragma unroll
      for (int n = 0; n < 4; ++n) {
        int row = wc + n * 16 + cl;
        bfr[n] = *(const bf16x8*)&Bs[row * 64 + (((kk * 4 + rq) ^ (row & 7)) * 8)];
      }
      #pragma unroll
      for (int m = 0; m < 4; ++m)
        #pragma unroll
        for (int n = 0; n < 4; ++n)
          acc[m][n] = MFMA16(af[m], bfr[n], acc[m][n]);
    }
  }

  const int gr0 = m0 + wr, gc0 = n0 + wc;
  #pragma unroll
  for (int m = 0; m < 4; ++m) {
    #pragma unroll
    for (int n = 0; n < 4; ++n) {
      int col = gc0 + n * 16 + cl;
      int rbase = gr0 + m * 16 + rq * 4;
      if constexpr (EPI == 0) {
        int sec = col / 384;
        int wcol = col - sec * 384;
        int hh = wcol >> 6, d = wcol & 63;
        int bidx = rbase >> 8, t0 = rbase & 255;
        if (sec == 2) {
          u16x4 pk;
          #pragma unroll
          for (int r = 0; r < 4; ++r) pk[r] = f2b(acc[m][n][r]);
          *(u16x4*)&vb[((size_t)(bidx * 6 + hh) * 64 + d) * 256 + t0] = pk;
        } else {
          short* dst = (sec == 0) ? qb : kb;
          float sc = (sec == 0) ? 0.125f : 1.0f;
          #pragma unroll
          for (int r = 0; r < 4; ++r)
            dst[((size_t)(bidx * 6 + hh) * 256 + t0 + r) * 64 + d] = (short)f2b(acc[m][n][r] * sc);
        }
      } else if constexpr (EPI == 1) {
        #pragma unroll
        for (int r = 0; r < 4; ++r) {
          size_t ix = (size_t)(rbase + r) * N + col;
          fout[ix] = acc[m][n][r] + bias[col] + resid[ix];
        }
      } else {
        #pragma unroll
        for (int r = 0; r < 4; ++r)
          bout[(size_t)(rbase + r) * N + col] = (short)f2b(fmaxf(acc[m][n][r] + bias[col], 0.f));
      }
    }
  }
}

// ---------------- attention: 1 block = ONE (b,h), all 256 q-rows ----------
// q,k layout [B,H,T,D]; v layout [B,H,D,T]. q pre-scaled by 1/8.
// K,V staged to LDS once; 4 waves; each wave does 16 q-rows per quarter,
// looping over 4 quarters. Q fragments all prefetched before the barrier.
__global__ __launch_bounds__(256) void attn_kernel(
    const short* __restrict__ qg, const short* __restrict__ kg,
    const short* __restrict__ vg, short* __restrict__ og)
{
  __shared__ short Ks[256 * 64];   // [s][d], swizzled (8 granules/row)
  __shared__ short Vs[64 * 256];   // [d][s], swizzled (32 granules/row, low3)
  __shared__ float Pb[4][16 * 36]; // per-wave P scratch, stride 36 floats
  const int tid = threadIdx.x;
  const int bh = blockIdx.x;
  const int w = tid >> 6, l = tid & 63;
  const int cl = l & 15, rq = l >> 4;
  const short* kgb = kg + (size_t)bh * 16384;
  const short* vgb = vg + (size_t)bh * 16384;
  #pragma unroll
  for (int i = 0; i < 8; ++i) {
    int slot = i * 256 + tid;
    int row = slot >> 3, g = slot & 7;
    gll16(kgb + row * 64 + (g ^ (row & 7)) * 8, &Ks[slot * 8]);
  }
  #pragma unroll
  for (int i = 0; i < 8; ++i) {
    int slot = i * 256 + tid;
    int row = slot >> 5, g = slot & 31;
    int gs = (g & 24) | ((g ^ row) & 7);
    gll16(vgb + row * 256 + gs * 8, &Vs[slot * 8]);
  }
  // prefetch all Q fragments (4 quarters x 2 halves) while staging is in flight
  bf16x8 qf0[4], qf1[4];
  #pragma unroll
  for (int qq = 0; qq < 4; ++qq) {
    const int qrow = qq * 64 + w * 16 + cl;
    const bf16x8* qp = (const bf16x8*)(qg + ((size_t)bh * 256 + qrow) * 64 + rq * 8);
    qf0[qq] = qp[0];
    qf1[qq] = qp[4];
  }
  const int b = bh / 6, hh = bh - b * 6;
  __syncthreads();

  for (int qq = 0; qq < 4; ++qq) {
    // S = Q K^T  (16 col-frags x f32x4)
    f32x4 s[16] = {};
    #pragma unroll
    for (int c = 0; c < 16; ++c) {
      int scol = c * 16 + cl;
      bf16x8 b0 = *(const bf16x8*)&Ks[scol * 64 + ((rq ^ (scol & 7)) * 8)];
      bf16x8 b1 = *(const bf16x8*)&Ks[scol * 64 + (((4 + rq) ^ (scol & 7)) * 8)];
      s[c] = MFMA16(qf0[qq], b0, s[c]);
      s[c] = MFMA16(qf1[qq], b1, s[c]);
    }
    // softmax along 256 cols; row r lives in 16-lane group (same rq)
    float mx[4], inv[4];
    #pragma unroll
    for (int r = 0; r < 4; ++r) {
      float m = s[0][r];
      #pragma unroll
      for (int c = 1; c < 16; ++c) m = fmaxf(m, s[c][r]);
      #pragma unroll
      for (int msk = 1; msk < 16; msk <<= 1) m = fmaxf(m, __shfl_xor(m, msk));
      mx[r] = m;
    }
    #pragma unroll
    for (int r = 0; r < 4; ++r) {
      float t = 0.f;
      #pragma unroll
      for (int c = 0; c < 16; ++c) { float e = __expf(s[c][r] - mx[r]); s[c][r] = e; t += e; }
      #pragma unroll
      for (int msk = 1; msk < 16; msk <<= 1) t += __shfl_xor(t, msk);
      inv[r] = 1.f / t;
    }
    #pragma unroll
    for (int c = 0; c < 16; ++c) {
      #pragma unroll
      for (int r = 0; r < 4; ++r) s[c][r] *= inv[r];
    }
    // O = P V  in 8 chunks of 32 s-positions (LDS round-trip P -> A-frag)
    f32x4 oacc[4] = {};
    float* Pw = Pb[w];
    #pragma unroll
    for (int ch = 0; ch < 8; ++ch) {
      #pragma unroll
      for (int r = 0; r < 4; ++r) {
        Pw[(4 * rq + r) * 36 + cl]      = s[2 * ch][r];
        Pw[(4 * rq + r) * 36 + 16 + cl] = s[2 * ch + 1][r];
      }
      f32x4 lo = *(const f32x4*)&Pw[cl * 36 + rq * 8];
      f32x4 hi = *(const f32x4*)&Pw[cl * 36 + rq * 8 + 4];
      bf16x8 pa;
      #pragma unroll
      for (int j = 0; j < 4; ++j) { pa[j] = (short)f2b(lo[j]); pa[j + 4] = (short)f2b(hi[j]); }
      #pragma unroll
      for (int n = 0; n < 4; ++n) {
        int vrow = n * 16 + cl;
        int gg = ch * 4 + rq;
        int gs = (gg & 24) | ((gg ^ vrow) & 7);
        bf16x8 vf = *(const bf16x8*)&Vs[vrow * 256 + gs * 8];
        oacc[n] = MFMA16(pa, vf, oacc[n]);
      }
    }
    // store O as [b][t][h*64+d]
    #pragma unroll
    for (int n = 0; n < 4; ++n) {
      #pragma unroll
      for (int r = 0; r < 4; ++r) {
        int trow = qq * 64 + w * 16 + 4 * rq + r;
        og[((size_t)(b * 256 + trow)) * 384 + hh * 64 + n * 16 + cl] = (short)f2b(oacc[n][r]);
      }
    }
  }
}

// ---------------- host ----------------
extern "C" void kernel_launch(void* const* d_in, const int* in_sizes, int n_in,
                              void* d_out, int out_size, void* d_ws, size_t ws_size,
                              hipStream_t stream) {
  const float* x   = (const float*)d_in[0];
  const float* Wq  = (const float*)d_in[1];
  const float* Wk  = (const float*)d_in[2];
  const float* Wv  = (const float*)d_in[3];
  const float* Wo  = (const float*)d_in[4];
  const float* bo  = (const float*)d_in[5];
  const float* W1  = (const float*)d_in[6];
  const float* b1  = (const float*)d_in[7];
  const float* W2  = (const float*)d_in[8];
  const float* b2  = (const float*)d_in[9];
  const float* g1  = (const float*)d_in[10];
  const float* be1 = (const float*)d_in[11];
  const float* g2  = (const float*)d_in[12];
  const float* be2 = (const float*)d_in[13];

  char* ws = (char*)d_ws;
  short* wqkvT = (short*)(ws);                 //  884736 B
  short* woT   = (short*)(ws + 884736);        //  294912 B
  short* w1T   = (short*)(ws + 1179648);       // 1179648 B
  short* w2T   = (short*)(ws + 2359296);       // 1179648 B
  short* bufA  = (short*)(ws + 3538944);       // 201326592 B shared region (shorts)
  short* h  = bufA;                            // LN1 out [0, 25165824)
  short* q  = bufA + 25165824;                 // [B,H,T,D]
  short* k  = bufA + 50331648;                 // [B,H,T,D]
  short* v  = bufA + 75497472;                 // [B,H,D,T]
  short* o  = bufA;                            // attn out, overlays h
  short* h2 = bufA + 25165824;                 // LN2 out, overlays q
  short* act = bufA + 50331648;                // FF1 act (32768 rows), overlays k,v
  float* out = (float*)d_out;                  // residual stream lives here after Wo

  prep_kernel<<<6912, 256, 0, stream>>>(Wq, Wk, Wv, Wo, W1, W2, wqkvT, woT, w1T, w2T);
  ln_kernel<<<16384, 256, 0, stream>>>(x, g1, be1, h);
  // QKV: [65536,384] x [1152,384]^T -> q,k,v   grid 9x256
  gemm_bt<0><<<9 * 256, 512, 0, stream>>>(h, wqkvT, 384, 6, 1152, 9,
      nullptr, nullptr, nullptr, nullptr, q, k, v);
  attn_kernel<<<1536, 256, 0, stream>>>(q, k, v, o);
  // Wo: out = o @ Wo + bo + x   grid 3x256
  gemm_bt<1><<<3 * 256, 512, 0, stream>>>(o, woT, 384, 6, 384, 3,
      bo, x, out, nullptr, nullptr, nullptr, nullptr);
  ln_kernel<<<16384, 256, 0, stream>>>(out, g2, be2, h2);
  for (int c = 0; c < 2; ++c) {
    const size_t roff = (size_t)c * 32768 * 384;
    const size_t ooff = (size_t)c * 32768 * 384;
    gemm_bt<2><<<12 * 128, 512, 0, stream>>>(h2 + roff, w1T, 384, 6, 1536, 12,
        b1, nullptr, nullptr, act, nullptr, nullptr, nullptr);
    gemm_bt<1><<<3 * 128, 512, 0, stream>>>(act, w2T, 1536, 24, 384, 3,
        b2, out + ooff, out + ooff, nullptr, nullptr, nullptr, nullptr);
  }
}

// Round 5
// 513.991 us; speedup vs baseline: 1.1813x; 1.1813x over previous
//
#include <hip/hip_runtime.h>

typedef __attribute__((ext_vector_type(8))) short bf16x8;
typedef __attribute__((ext_vector_type(4))) float f32x4;
typedef __attribute__((ext_vector_type(4))) unsigned short u16x4;
typedef __attribute__((ext_vector_type(4))) unsigned int u32x4;

#define DEVFN static __device__ __forceinline__

DEVFN unsigned short f2b(float f) {   // f32 -> bf16, round-to-nearest-even
  union { float f; unsigned u; } x; x.f = f;
  unsigned r = x.u + 0x7FFFu + ((x.u >> 16) & 1u);
  return (unsigned short)(r >> 16);
}

DEVFN unsigned cvtpk(float lo, float hi) {  // {bf16(hi)<<16 | bf16(lo)}
  unsigned r;
  asm("v_cvt_pk_bf16_f32 %0, %1, %2" : "=v"(r) : "v"(lo), "v"(hi));
  return r;
}

DEVFN void gll16(const void* g, void* l) {  // async global->LDS, 16B per lane
  __builtin_amdgcn_global_load_lds(
      (const __attribute__((address_space(1))) unsigned int*)g,
      (__attribute__((address_space(3))) unsigned int*)l, 16, 0, 0);
}

#define MFMA16(a, b, c) __builtin_amdgcn_mfma_f32_16x16x32_bf16((a), (b), (c), 0, 0, 0)

// ---------------- prep: cast + transpose weights to bf16 ----------------
__global__ __launch_bounds__(256) void prep_kernel(
    const float* __restrict__ Wq, const float* __restrict__ Wk, const float* __restrict__ Wv,
    const float* __restrict__ Wo, const float* __restrict__ W1, const float* __restrict__ W2,
    short* __restrict__ wqkvT, short* __restrict__ woT,
    short* __restrict__ w1T, short* __restrict__ w2T)
{
  int idx = blockIdx.x * 256 + threadIdx.x;
  if (idx < 442368) {
    int n = idx / 384, kk = idx - n * 384;
    int sec = n / 384, ww = n - sec * 384;
    const float* s = sec == 0 ? Wq : (sec == 1 ? Wk : Wv);
    wqkvT[idx] = (short)f2b(s[kk * 384 + ww]);
  } else if (idx < 589824) {
    int j = idx - 442368;
    int n = j / 384, kk = j - n * 384;
    woT[j] = (short)f2b(Wo[kk * 384 + n]);
  } else if (idx < 1179648) {
    int j = idx - 589824;
    int n = j / 384, kk = j - n * 384;
    w1T[j] = (short)f2b(W1[kk * 1536 + n]);
  } else if (idx < 1769472) {
    int j = idx - 1179648;
    int n = j / 1536, kk = j - n * 1536;
    w2T[j] = (short)f2b(W2[kk * 384 + n]);
  }
}

// ---------------- LayerNorm: f32 in -> bf16 out, 1 wave per row of 384 ----
__global__ __launch_bounds__(256) void ln_kernel(
    const float* __restrict__ x, const float* __restrict__ g, const float* __restrict__ b,
    short* __restrict__ out)
{
  int row = blockIdx.x * 4 + (threadIdx.x >> 6);
  int l = threadIdx.x & 63;
  const float* xr = x + (size_t)row * 384;
  float v[6], s = 0.f, s2 = 0.f;
  #pragma unroll
  for (int i = 0; i < 6; ++i) { v[i] = xr[l + 64 * i]; s += v[i]; s2 += v[i] * v[i]; }
  #pragma unroll
  for (int m = 1; m < 64; m <<= 1) { s += __shfl_xor(s, m); s2 += __shfl_xor(s2, m); }
  float mu = s * (1.f / 384.f);
  float rs = rsqrtf(s2 * (1.f / 384.f) - mu * mu + 1e-5f);
  short* orow = out + (size_t)row * 384;
  #pragma unroll
  for (int i = 0; i < 6; ++i) {
    int c = l + 64 * i;
    orow[c] = (short)f2b((v[i] - mu) * rs * g[c] + b[c]);
  }
}

// ---------------- GEMM: C[M,N] = A[M,K] * BT[N,K]^T, bf16 MFMA ------------
// 256x128 tile, BK=64, 512 threads = 8 waves (4x2), wave = 64x64 (4x4 frags).
// 1D grid, XCD-chunked bijective swizzle, x-fastest within chunk.
// LDS XOR-swizzled (granule ^= row&7) via pre-swizzled global source.
// EPI 0: QKV split (q scaled 0.125, v stored [B,H,D,T])
// EPI 1: f32 out = acc + bias[col] + resid[row,col]   (fout may alias resid)
// EPI 2: bf16 out = relu(acc + bias[col])
template<int EPI>
__global__ __launch_bounds__(512) void gemm_bt(
    const short* __restrict__ A, const short* __restrict__ BT,
    int K, int kt, int N, int nx,
    const float* __restrict__ bias, const float* __restrict__ resid,
    float* __restrict__ fout, short* __restrict__ bout,
    short* __restrict__ qb, short* __restrict__ kb, short* __restrict__ vb)
{
  __shared__ short As[256 * 64];
  __shared__ short Bs[128 * 64];
  const int tid = threadIdx.x;
  const int l = tid & 63, w = tid >> 6;
  const int cl = l & 15, rq = l >> 4;
  const int wr = (w >> 1) * 64, wc = (w & 1) * 64;

  // bijective XCD-chunk swizzle
  const int nwg = gridDim.x, bid = blockIdx.x;
  const int q8 = nwg >> 3, r8 = nwg & 7;
  const int xcd = bid & 7, ii = bid >> 3;
  const int wg = (xcd < r8) ? xcd * (q8 + 1) + ii : r8 * (q8 + 1) + (xcd - r8) * q8 + ii;
  const int bx = wg % nx, by = wg / nx;

  const int m0 = by * 256, n0 = bx * 128;
  const short* Ab = A + (size_t)m0 * K;
  const short* Bb = BT + (size_t)n0 * K;

  f32x4 acc[4][4] = {};

  for (int ks = 0; ks < kt; ++ks) {
    const int k0 = ks * 64;
    __syncthreads();
    #pragma unroll
    for (int i = 0; i < 4; ++i) {
      int slot = i * 512 + tid;
      int row = slot >> 3, g = slot & 7;
      int gs = g ^ (row & 7);
      gll16(Ab + (size_t)row * K + k0 + gs * 8, &As[slot * 8]);
    }
    #pragma unroll
    for (int i = 0; i < 2; ++i) {
      int slot = i * 512 + tid;
      int row = slot >> 3, g = slot & 7;
      int gs = g ^ (row & 7);
      gll16(Bb + (size_t)row * K + k0 + gs * 8, &Bs[slot * 8]);
    }
    __syncthreads();
    #pragma unroll
    for (int kk = 0; kk < 2; ++kk) {
      bf16x8 af[4], bfr[4];
      #pragma unroll
      for (int m = 0; m < 4; ++m) {
        int row = wr + m * 16 + cl;
        af[m] = *(const bf16x8*)&As[row * 64 + (((kk * 4 + rq) ^ (row & 7)) * 8)];
      }
      #pragma unroll
      for (int n = 0; n < 4; ++n) {
        int row = wc + n * 16 + cl;
        bfr[n] = *(const bf16x8*)&Bs[row * 64 + (((kk * 4 + rq) ^ (row & 7)) * 8)];
      }
      #pragma unroll
      for (int m = 0; m < 4; ++m)
        #pragma unroll
        for (int n = 0; n < 4; ++n)
          acc[m][n] = MFMA16(af[m], bfr[n], acc[m][n]);
    }
  }

  const int gr0 = m0 + wr, gc0 = n0 + wc;
  #pragma unroll
  for (int m = 0; m < 4; ++m) {
    #pragma unroll
    for (int n = 0; n < 4; ++n) {
      int col = gc0 + n * 16 + cl;
      int rbase = gr0 + m * 16 + rq * 4;
      if constexpr (EPI == 0) {
        int sec = col / 384;
        int wcol = col - sec * 384;
        int hh = wcol >> 6, d = wcol & 63;
        int bidx = rbase >> 8, t0 = rbase & 255;
        if (sec == 2) {
          u16x4 pk;
          #pragma unroll
          for (int r = 0; r < 4; ++r) pk[r] = f2b(acc[m][n][r]);
          *(u16x4*)&vb[((size_t)(bidx * 6 + hh) * 64 + d) * 256 + t0] = pk;
        } else {
          short* dst = (sec == 0) ? qb : kb;
          float sc = (sec == 0) ? 0.125f : 1.0f;
          #pragma unroll
          for (int r = 0; r < 4; ++r)
            dst[((size_t)(bidx * 6 + hh) * 256 + t0 + r) * 64 + d] = (short)f2b(acc[m][n][r] * sc);
        }
      } else if constexpr (EPI == 1) {
        #pragma unroll
        for (int r = 0; r < 4; ++r) {
          size_t ix = (size_t)(rbase + r) * N + col;
          fout[ix] = acc[m][n][r] + bias[col] + resid[ix];
        }
      } else {
        #pragma unroll
        for (int r = 0; r < 4; ++r)
          bout[(size_t)(rbase + r) * N + col] = (short)f2b(fmaxf(acc[m][n][r] + bias[col], 0.f));
      }
    }
  }
}

// ---------------- attention: 1 block = ONE (b,h), 1024 thr = 16 waves -----
// q,k layout [B,H,T,D]; v layout [B,H,D,T]. q pre-scaled by 1/8.
// K,V staged to LDS once (64KB); wave w owns q-rows w*16..w*16+15.
// Swapped QK^T (S^T in regs, lane holds kpos=c*16+4rq+r for qrow=cl),
// register softmax (deferred normalization), P->A-frag via cvt_pk+bpermute.
__global__ __launch_bounds__(1024) void attn_kernel(
    const short* __restrict__ qg, const short* __restrict__ kg,
    const short* __restrict__ vg, short* __restrict__ og)
{
  __shared__ short Ks[256 * 64];   // [s][d], swizzled (8 granules/row)
  __shared__ short Vs[64 * 256];   // [d][s], swizzled (32 granules/row, low3)
  const int tid = threadIdx.x;
  const int bh = blockIdx.x;
  const int w = tid >> 6, l = tid & 63;
  const int cl = l & 15, rq = l >> 4;
  const short* kgb = kg + (size_t)bh * 16384;
  const short* vgb = vg + (size_t)bh * 16384;
  #pragma unroll
  for (int i = 0; i < 2; ++i) {
    int slot = i * 1024 + tid;
    int row = slot >> 3, g = slot & 7;
    gll16(kgb + row * 64 + (g ^ (row & 7)) * 8, &Ks[slot * 8]);
  }
  #pragma unroll
  for (int i = 0; i < 2; ++i) {
    int slot = i * 1024 + tid;
    int row = slot >> 5, g = slot & 31;
    int gs = (g & 24) | ((g ^ row) & 7);
    gll16(vgb + row * 256 + gs * 8, &Vs[slot * 8]);
  }
  // Q B-frags for this wave's 16 rows: lane holds Q[qrow=cl][d=rq*8+j] (+32)
  const int qrow = w * 16 + cl;
  const bf16x8* qp = (const bf16x8*)(qg + ((size_t)bh * 256 + qrow) * 64 + rq * 8);
  bf16x8 qf0 = qp[0], qf1 = qp[4];
  const int b = bh / 6, hh = bh - b * 6;
  __syncthreads();

  // S^T = (K)(Q)^T: s[c][r] = S[kpos=c*16+4rq+r][qrow=cl] (wave's 16 rows)
  f32x4 s[16] = {};
  #pragma unroll
  for (int c = 0; c < 16; ++c) {
    int srow = c * 16 + cl;
    bf16x8 k0 = *(const bf16x8*)&Ks[srow * 64 + ((rq ^ (srow & 7)) * 8)];
    bf16x8 k1 = *(const bf16x8*)&Ks[srow * 64 + (((4 + rq) ^ (srow & 7)) * 8)];
    s[c] = MFMA16(k0, qf0, s[c]);
    s[c] = MFMA16(k1, qf1, s[c]);
  }
  // row max over all 256 kpos for qrow=cl: tree over 64 regs + xor16,32
  float mr[8];
  #pragma unroll
  for (int c = 0; c < 8; ++c)
    mr[c] = fmaxf(fmaxf(fmaxf(s[2*c][0], s[2*c][1]), fmaxf(s[2*c][2], s[2*c][3])),
                  fmaxf(fmaxf(s[2*c+1][0], s[2*c+1][1]), fmaxf(s[2*c+1][2], s[2*c+1][3])));
  float m = fmaxf(fmaxf(fmaxf(mr[0], mr[1]), fmaxf(mr[2], mr[3])),
                  fmaxf(fmaxf(mr[4], mr[5]), fmaxf(mr[6], mr[7])));
  m = fmaxf(m, __shfl_xor(m, 16));
  m = fmaxf(m, __shfl_xor(m, 32));
  // exp (unnormalized P) + row sum
  float tc[16];
  #pragma unroll
  for (int c = 0; c < 16; ++c) {
    #pragma unroll
    for (int r = 0; r < 4; ++r) s[c][r] = __expf(s[c][r] - m);
    tc[c] = (s[c][0] + s[c][1]) + (s[c][2] + s[c][3]);
  }
  float t = ((tc[0]+tc[1])+(tc[2]+tc[3])) + ((tc[4]+tc[5])+(tc[6]+tc[7]))
          + ((tc[8]+tc[9])+(tc[10]+tc[11])) + ((tc[12]+tc[13])+(tc[14]+tc[15]));
  t += __shfl_xor(t, 16);
  t += __shfl_xor(t, 32);
  const float inv = 1.f / t;   // for qrow = cl

  // O = P V: per 32-kpos chunk, build P A-frag in-register
  // target lane (rq,cl): pa j = P[qrow=cl][kpos=32ch+8rq+j]
  //   words 0,1 from srclane ((2rq)&3)*16+cl; words 2,3 from ((2rq+1)&3)*16+cl
  //   register pair X0/X1 (c=2ch) for rq<2 targets, X2/X3 (c=2ch+1) for rq>=2
  f32x4 oacc[4] = {};
  const int idx1 = (((2 * rq) & 3) * 16 + cl) << 2;
  const int idx2 = (((2 * rq + 1) & 3) * 16 + cl) << 2;
  const bool up = rq >= 2;
  #pragma unroll
  for (int ch = 0; ch < 8; ++ch) {
    int X0 = (int)cvtpk(s[2*ch][0], s[2*ch][1]);
    int X1 = (int)cvtpk(s[2*ch][2], s[2*ch][3]);
    int X2 = (int)cvtpk(s[2*ch+1][0], s[2*ch+1][1]);
    int X3 = (int)cvtpk(s[2*ch+1][2], s[2*ch+1][3]);
    int lo0 = __builtin_amdgcn_ds_bpermute(idx1, X0);
    int lo1 = __builtin_amdgcn_ds_bpermute(idx1, X1);
    int hi0 = __builtin_amdgcn_ds_bpermute(idx1, X2);
    int hi1 = __builtin_amdgcn_ds_bpermute(idx1, X3);
    int lo2 = __builtin_amdgcn_ds_bpermute(idx2, X0);
    int lo3 = __builtin_amdgcn_ds_bpermute(idx2, X1);
    int hi2 = __builtin_amdgcn_ds_bpermute(idx2, X2);
    int hi3 = __builtin_amdgcn_ds_bpermute(idx2, X3);
    u32x4 words;
    words[0] = (unsigned)(up ? hi0 : lo0);
    words[1] = (unsigned)(up ? hi1 : lo1);
    words[2] = (unsigned)(up ? hi2 : lo2);
    words[3] = (unsigned)(up ? hi3 : lo3);
    bf16x8 pa = __builtin_bit_cast(bf16x8, words);
    #pragma unroll
    for (int n = 0; n < 4; ++n) {
      int vrow = n * 16 + cl;
      int gg = ch * 4 + rq;
      int gs = (gg & 24) | ((gg ^ vrow) & 7);
      bf16x8 vf = *(const bf16x8*)&Vs[vrow * 256 + gs * 8];
      oacc[n] = MFMA16(pa, vf, oacc[n]);
    }
  }
  // normalize with inv transported to output layout (row = 4rq+r)
  float invr[4];
  #pragma unroll
  for (int r = 0; r < 4; ++r) invr[r] = __shfl(inv, 4 * rq + r);
  // store O as [b][t][h*64+d]
  #pragma unroll
  for (int n = 0; n < 4; ++n) {
    #pragma unroll
    for (int r = 0; r < 4; ++r) {
      int trow = w * 16 + 4 * rq + r;
      og[((size_t)(b * 256 + trow)) * 384 + hh * 64 + n * 16 + cl] =
          (short)f2b(oacc[n][r] * invr[r]);
    }
  }
}

// ---------------- host ----------------
extern "C" void kernel_launch(void* const* d_in, const int* in_sizes, int n_in,
                              void* d_out, int out_size, void* d_ws, size_t ws_size,
                              hipStream_t stream) {
  const float* x   = (const float*)d_in[0];
  const float* Wq  = (const float*)d_in[1];
  const float* Wk  = (const float*)d_in[2];
  const float* Wv  = (const float*)d_in[3];
  const float* Wo  = (const float*)d_in[4];
  const float* bo  = (const float*)d_in[5];
  const float* W1  = (const float*)d_in[6];
  const float* b1  = (const float*)d_in[7];
  const float* W2  = (const float*)d_in[8];
  const float* b2  = (const float*)d_in[9];
  const float* g1  = (const float*)d_in[10];
  const float* be1 = (const float*)d_in[11];
  const float* g2  = (const float*)d_in[12];
  const float* be2 = (const float*)d_in[13];

  char* ws = (char*)d_ws;
  short* wqkvT = (short*)(ws);                 //  884736 B
  short* woT   = (short*)(ws + 884736);        //  294912 B
  short* w1T   = (short*)(ws + 1179648);       // 1179648 B
  short* w2T   = (short*)(ws + 2359296);       // 1179648 B
  short* bufA  = (short*)(ws + 3538944);       // 201326592 B shared region (shorts)
  short* h  = bufA;                            // LN1 out [0, 25165824)
  short* q  = bufA + 25165824;                 // [B,H,T,D]
  short* k  = bufA + 50331648;                 // [B,H,T,D]
  short* v  = bufA + 75497472;                 // [B,H,D,T]
  short* o  = bufA;                            // attn out, overlays h
  short* h2 = bufA + 25165824;                 // LN2 out, overlays q
  short* act = bufA + 50331648;                // FF1 act (32768 rows), overlays k,v
  float* out = (float*)d_out;                  // residual stream lives here after Wo

  prep_kernel<<<6912, 256, 0, stream>>>(Wq, Wk, Wv, Wo, W1, W2, wqkvT, woT, w1T, w2T);
  ln_kernel<<<16384, 256, 0, stream>>>(x, g1, be1, h);
  // QKV: [65536,384] x [1152,384]^T -> q,k,v   grid 9x256
  gemm_bt<0><<<9 * 256, 512, 0, stream>>>(h, wqkvT, 384, 6, 1152, 9,
      nullptr, nullptr, nullptr, nullptr, q, k, v);
  attn_kernel<<<1536, 1024, 0, stream>>>(q, k, v, o);
  // Wo: out = o @ Wo + bo + x   grid 3x256
  gemm_bt<1><<<3 * 256, 512, 0, stream>>>(o, woT, 384, 6, 384, 3,
      bo, x, out, nullptr, nullptr, nullptr, nullptr);
  ln_kernel<<<16384, 256, 0, stream>>>(out, g2, be2, h2);
  for (int c = 0; c < 2; ++c) {
    const size_t roff = (size_t)c * 32768 * 384;
    const size_t ooff = (size_t)c * 32768 * 384;
    gemm_bt<2><<<12 * 128, 512, 0, stream>>>(h2 + roff, w1T, 384, 6, 1536, 12,
        b1, nullptr, nullptr, act, nullptr, nullptr, nullptr);
    gemm_bt<1><<<3 * 128, 512, 0, stream>>>(act, w2T, 1536, 24, 384, 3,
        b2, out + ooff, out + ooff, nullptr, nullptr, nullptr, nullptr);
  }
}